// Round 1
// baseline (470.429 us; speedup 1.0000x reference)
//
#include <hip/hip_runtime.h>

// LIF timestep (SpikeLayer.update_neurons), shape (16,56,56,256) fp32.
// Pure elementwise, memory-bound: 5 inputs read, 6 outputs written.
// Constants from the reference:
//   V_THRESH = 1.0, DT = 1.0, TAU_REFRAC = 2.0, TIME = 0.5
// spikes in {0, V_THRESH} so the reference's (spikes < 0) branch is dead.

constexpr float V_THRESH   = 1.0f;
constexpr float TIME_      = 0.5f;
constexpr float REFRAC_SET = TIME_ + 2.0f;  // TIME + TAU_REFRAC = 2.5

__global__ __launch_bounds__(256) void spike_lif_kernel(
    const float4* __restrict__ impulse,
    const float4* __restrict__ mem,
    const float4* __restrict__ mem_acc,
    const float4* __restrict__ refrac,
    const float4* __restrict__ counts,
    float4* __restrict__ out,   // 6 tensors stacked: [spikes, mem, mem_acc, refrac, counts, spiketrain]
    int n4)                     // element count / 4
{
    int i = blockIdx.x * blockDim.x + threadIdx.x;
    if (i >= n4) return;

    float4 imp = impulse[i];
    float4 m   = mem[i];
    float4 ma  = mem_acc[i];
    float4 r   = refrac[i];
    float4 c   = counts[i];

    float4 v_spk, v_mem, v_macc, v_ref, v_cnt, v_trn;

    const float* fi = reinterpret_cast<const float*>(&imp);
    const float* fm = reinterpret_cast<const float*>(&m);
    const float* fa = reinterpret_cast<const float*>(&ma);
    const float* fr = reinterpret_cast<const float*>(&r);
    const float* fc = reinterpret_cast<const float*>(&c);
    float* o_spk = reinterpret_cast<float*>(&v_spk);
    float* o_mem = reinterpret_cast<float*>(&v_mem);
    float* o_mac = reinterpret_cast<float*>(&v_macc);
    float* o_ref = reinterpret_cast<float*>(&v_ref);
    float* o_cnt = reinterpret_cast<float*>(&v_cnt);
    float* o_trn = reinterpret_cast<float*>(&v_trn);

#pragma unroll
    for (int k = 0; k < 4; ++k) {
        // get_new_mem: mask impulse for refractory neurons
        float mi      = (fr[k] > TIME_) ? 0.0f : fi[k];
        float new_mem = fm[k] + mi;
        float new_acc = fa[k] + mi;
        // linear_activation
        bool  fired   = (new_mem >= V_THRESH);
        float spikes  = fired ? V_THRESH : 0.0f;
        // reset-by-subtraction (spikes<0 branch is dead: spikes in {0,1})
        float mem_o   = fired ? (new_mem - V_THRESH) : new_mem;
        // refractory update
        float ref_o   = fired ? REFRAC_SET : fr[k];
        // spike counting
        float cnt_o   = fc[k] + (fired ? 1.0f : 0.0f);
        // spiketrain: spike time
        float trn_o   = spikes * TIME_;

        o_spk[k] = spikes;
        o_mem[k] = mem_o;
        o_mac[k] = new_acc;
        o_ref[k] = ref_o;
        o_cnt[k] = cnt_o;
        o_trn[k] = trn_o;
    }

    out[0LL * n4 + i] = v_spk;
    out[1LL * n4 + i] = v_mem;
    out[2LL * n4 + i] = v_macc;
    out[3LL * n4 + i] = v_ref;
    out[4LL * n4 + i] = v_cnt;
    out[5LL * n4 + i] = v_trn;
}

extern "C" void kernel_launch(void* const* d_in, const int* in_sizes, int n_in,
                              void* d_out, int out_size, void* d_ws, size_t ws_size,
                              hipStream_t stream) {
    const float4* impulse = (const float4*)d_in[0];
    const float4* mem     = (const float4*)d_in[1];
    const float4* mem_acc = (const float4*)d_in[2];
    const float4* refrac  = (const float4*)d_in[3];
    const float4* counts  = (const float4*)d_in[4];
    float4* out = (float4*)d_out;

    const int n  = in_sizes[0];        // 12,845,056 (divisible by 4)
    const int n4 = n / 4;              // 3,211,264
    const int block = 256;
    const int grid  = (n4 + block - 1) / block;

    spike_lif_kernel<<<grid, block, 0, stream>>>(impulse, mem, mem_acc, refrac,
                                                 counts, out, n4);
}

// Round 3
// 470.332 us; speedup vs baseline: 1.0002x; 1.0002x over previous
//
#include <hip/hip_runtime.h>

// LIF timestep (SpikeLayer.update_neurons), shape (16,56,56,256) fp32.
// Pure elementwise streaming: 5 inputs read once, 6 outputs written once,
// zero reuse -> nontemporal loads/stores to bypass L2/L3 allocation.
// Constants: V_THRESH=1.0, DT=1.0, TAU_REFRAC=2.0, TIME=0.5.
// spikes in {0, V_THRESH} so the reference's (spikes < 0) branch is dead.
//
// NOTE: __builtin_nontemporal_* rejects HIP_vector_type<float,4>; use a
// native clang ext_vector_type instead.

typedef float f32x4 __attribute__((ext_vector_type(4)));

constexpr float V_THRESH   = 1.0f;
constexpr float TIME_      = 0.5f;
constexpr float REFRAC_SET = TIME_ + 2.0f;  // TIME + TAU_REFRAC = 2.5

__global__ __launch_bounds__(256) void spike_lif_kernel(
    const f32x4* __restrict__ impulse,
    const f32x4* __restrict__ mem,
    const f32x4* __restrict__ mem_acc,
    const f32x4* __restrict__ refrac,
    const f32x4* __restrict__ counts,
    f32x4* __restrict__ out,    // 6 tensors stacked: [spikes, mem, mem_acc, refrac, counts, spiketrain]
    int n4)                     // element count / 4
{
    int i = blockIdx.x * blockDim.x + threadIdx.x;
    if (i >= n4) return;

    // Nontemporal loads: no reuse, don't allocate in cache.
    f32x4 imp = __builtin_nontemporal_load(&impulse[i]);
    f32x4 m   = __builtin_nontemporal_load(&mem[i]);
    f32x4 ma  = __builtin_nontemporal_load(&mem_acc[i]);
    f32x4 r   = __builtin_nontemporal_load(&refrac[i]);
    f32x4 c   = __builtin_nontemporal_load(&counts[i]);

    f32x4 v_spk, v_mem, v_macc, v_ref, v_cnt, v_trn;

#pragma unroll
    for (int k = 0; k < 4; ++k) {
        // get_new_mem: mask impulse for refractory neurons
        float mi      = (r[k] > TIME_) ? 0.0f : imp[k];
        float new_mem = m[k] + mi;
        float new_acc = ma[k] + mi;
        // linear_activation
        bool  fired   = (new_mem >= V_THRESH);
        float spikes  = fired ? V_THRESH : 0.0f;
        // reset-by-subtraction (spikes<0 branch is dead: spikes in {0,1})
        float mem_o   = fired ? (new_mem - V_THRESH) : new_mem;
        // refractory update
        float ref_o   = fired ? REFRAC_SET : r[k];
        // spike counting
        float cnt_o   = c[k] + (fired ? 1.0f : 0.0f);
        // spiketrain: spike time
        float trn_o   = spikes * TIME_;

        v_spk[k]  = spikes;
        v_mem[k]  = mem_o;
        v_macc[k] = new_acc;
        v_ref[k]  = ref_o;
        v_cnt[k]  = cnt_o;
        v_trn[k]  = trn_o;
    }

    // Nontemporal stores: streaming writes, never re-read.
    __builtin_nontemporal_store(v_spk,  &out[0LL * n4 + i]);
    __builtin_nontemporal_store(v_mem,  &out[1LL * n4 + i]);
    __builtin_nontemporal_store(v_macc, &out[2LL * n4 + i]);
    __builtin_nontemporal_store(v_ref,  &out[3LL * n4 + i]);
    __builtin_nontemporal_store(v_cnt,  &out[4LL * n4 + i]);
    __builtin_nontemporal_store(v_trn,  &out[5LL * n4 + i]);
}

extern "C" void kernel_launch(void* const* d_in, const int* in_sizes, int n_in,
                              void* d_out, int out_size, void* d_ws, size_t ws_size,
                              hipStream_t stream) {
    const f32x4* impulse = (const f32x4*)d_in[0];
    const f32x4* mem     = (const f32x4*)d_in[1];
    const f32x4* mem_acc = (const f32x4*)d_in[2];
    const f32x4* refrac  = (const f32x4*)d_in[3];
    const f32x4* counts  = (const f32x4*)d_in[4];
    f32x4* out = (f32x4*)d_out;

    const int n  = in_sizes[0];        // 12,845,056 (divisible by 4)
    const int n4 = n / 4;              // 3,211,264
    const int block = 256;
    const int grid  = (n4 + block - 1) / block;

    spike_lif_kernel<<<grid, block, 0, stream>>>(impulse, mem, mem_acc, refrac,
                                                 counts, out, n4);
}